// Round 14
// baseline (322.700 us; speedup 1.0000x reference)
//
#include <hip/hip_runtime.h>
#include <hip/hip_bf16.h>
#include <cstddef>
#include <cstdint>

constexpr int T  = 2048;
constexpr int B  = 4;
constexpr int C  = 1024;
constexpr int H  = 16;
constexpr int DK = 64;
constexpr int M  = T * B;   // 8192
constexpr int NT = T / 64;  // 32 KV tiles

typedef __attribute__((ext_vector_type(8))) short bf16x8;
typedef __attribute__((ext_vector_type(4))) float f32x4;
typedef __attribute__((ext_vector_type(4))) unsigned short u16x4;
typedef __attribute__((ext_vector_type(8))) unsigned short u16x8;

__device__ inline unsigned short f2bf(float f) {
    union { float f; uint32_t u; } v; v.f = f;
    uint32_t u = v.u + 0x7fff + ((v.u >> 16) & 1);  // RNE
    return (unsigned short)(u >> 16);
}
__device__ inline float bf2f(unsigned short h) {
    union { uint32_t u; float f; } v; v.u = (uint32_t)h << 16;
    return v.f;
}
// HW packed f32->bf16 pair (no builtin on gfx950; T12 recipe)
__device__ inline uint32_t cvtpk_bf16(float lo, float hi) {
    uint32_t r;
    asm("v_cvt_pk_bf16_f32 %0, %1, %2" : "=v"(r) : "v"(lo), "v"(hi));
    return r;
}
// compiler-level full memory fence (no instruction emitted)
__device__ inline void cfence() { asm volatile("" ::: "memory"); }

// Raw workgroup barrier WITHOUT the vmcnt(0) drain __syncthreads emits.
__device__ inline void block_sync_lds() {
    __builtin_amdgcn_sched_barrier(0);
    asm volatile("s_waitcnt lgkmcnt(0)" ::: "memory");
    __builtin_amdgcn_sched_barrier(0);
    __builtin_amdgcn_s_barrier();
    __builtin_amdgcn_sched_barrier(0);
}

// global -> LDS direct DMA, 16B per lane.
__device__ inline void gload_lds16(const void* g, void* l) {
    auto gp = reinterpret_cast<const __attribute__((address_space(1))) char*>(
        reinterpret_cast<uintptr_t>(g));
    auto lp = reinterpret_cast<__attribute__((address_space(3))) char*>(
        reinterpret_cast<uintptr_t>(l));
    __builtin_amdgcn_global_load_lds(gp, lp, 16, 0, 0);
}

// ---------------------------------------------------------------------------
// Weight converters (small, ~5 us total). convert_in is ELIMINATED: qkv_gemm
// now reads fp32 inputs directly and converts during staging.
// ---------------------------------------------------------------------------
__global__ __launch_bounds__(256) void convert_w(const float* __restrict__ wq,
                                                 const float* __restrict__ wk,
                                                 const float* __restrict__ wv,
                                                 unsigned short* __restrict__ dst) {
    const float* s = blockIdx.y == 0 ? wq : (blockIdx.y == 1 ? wk : wv);
    unsigned short* d = dst + (size_t)blockIdx.y * C * C;
    const size_t i = ((size_t)blockIdx.x * 256 + threadIdx.x) * 8;
    const float4 a = *(const float4*)(s + i);
    const float4 b = *(const float4*)(s + i + 4);
    u16x8 o;
    o[0] = f2bf(a.x); o[1] = f2bf(a.y); o[2] = f2bf(a.z); o[3] = f2bf(a.w);
    o[4] = f2bf(b.x); o[5] = f2bf(b.y); o[6] = f2bf(b.z); o[7] = f2bf(b.w);
    *(u16x8*)(d + i) = o;
}

__global__ __launch_bounds__(256) void convert_wo(const float* __restrict__ wo,
                                                  unsigned short* __restrict__ hi,
                                                  unsigned short* __restrict__ lo) {
    const size_t i = ((size_t)blockIdx.x * 256 + threadIdx.x) * 8;
#pragma unroll
    for (int j = 0; j < 8; j++) {
        const float x = wo[i + j];
        const unsigned short h = f2bf(x);
        hi[i + j] = h;
        lo[i + j] = f2bf(x - bf2f(h));
    }
}

// ---------------------------------------------------------------------------
// Fused QKV projection GEMM — now reads fp32 A directly (convert_in fused).
// A reg-staged: 4x float4 loads -> v_cvt_pk_bf16_f32 -> 2x b128 ds_write.
// W (bf16) staged via gload_lds as before. R7 2-barrier structure (the R12
// dbuf was neutral at system level; prefer the simpler proven loop).
// Q scale folds 1/sqrt(DK) * log2(e) for the exp2-based softmax.
// ---------------------------------------------------------------------------
__global__ __launch_bounds__(256) void qkv_gemm(
        const float* __restrict__ Aq,
        const float* __restrict__ Ak,
        const float* __restrict__ Av,
        const unsigned short* __restrict__ W,
        const float* __restrict__ bq, const float* __restrict__ bk,
        const float* __restrict__ bv,
        unsigned short* __restrict__ Qb, unsigned short* __restrict__ Kb,
        unsigned short* __restrict__ Vb) {
    __shared__ __align__(16) unsigned short As[128][32];
    __shared__ __align__(16) unsigned short Ws[128][32];

    const int tid = threadIdx.x;
    const int m0 = blockIdx.x * 128;
    const int n0 = blockIdx.y * 128;
    const int w = tid >> 6, lane = tid & 63;
    const int g = lane >> 4, c16 = lane & 15;
    const int wr = (w >> 1) * 64, wc = (w & 1) * 64;

    const int which = n0 >> 10;  // 0=Q 1=K 2=V (no straddle)
    const float* A = which == 0 ? Aq : (which == 1 ? Ak : Av);

    // A staging map: 2 threads per row, 64B fp32 each (-> 32B bf16)
    const int ar = tid >> 1;           // row 0..127
    const int ab = (tid & 1) * 16;     // col base (fp32 elems == bf16 elems)

    f32x4 acc[4][4] = {};

    for (int k0 = 0; k0 < C; k0 += 32) {
        __syncthreads();
        // W: bf16 global -> LDS DMA (2 x 16B chunks per thread)
#pragma unroll
        for (int half = 0; half < 2; half++) {
            const int chunk = tid + half * 256;
            const int r = chunk >> 2, s = chunk & 3;
            gload_lds16(W + (size_t)(n0 + r) * C + k0 + s * 8,
                        (char*)&Ws[0][0] + chunk * 16);
        }
        // A: fp32 global -> regs -> cvt_pk bf16 -> LDS
        {
            const float* Ap = A + (size_t)(m0 + ar) * C + k0 + ab;
            const float4 a0 = *(const float4*)(Ap + 0);
            const float4 a1 = *(const float4*)(Ap + 4);
            const float4 a2 = *(const float4*)(Ap + 8);
            const float4 a3 = *(const float4*)(Ap + 12);
            uint4 w0, w1;
            w0.x = cvtpk_bf16(a0.x, a0.y); w0.y = cvtpk_bf16(a0.z, a0.w);
            w0.z = cvtpk_bf16(a1.x, a1.y); w0.w = cvtpk_bf16(a1.z, a1.w);
            w1.x = cvtpk_bf16(a2.x, a2.y); w1.y = cvtpk_bf16(a2.z, a2.w);
            w1.z = cvtpk_bf16(a3.x, a3.y); w1.w = cvtpk_bf16(a3.z, a3.w);
            *(uint4*)&As[ar][ab] = w0;
            *(uint4*)&As[ar][ab + 8] = w1;
        }
        __syncthreads();  // ds_writes (lgkm) + gload_lds (vmcnt) both drained

        bf16x8 af[4], bfr[4];
#pragma unroll
        for (int mf = 0; mf < 4; mf++)
            af[mf] = *(const bf16x8*)&As[wr + mf * 16 + c16][g * 8];
#pragma unroll
        for (int nf = 0; nf < 4; nf++)
            bfr[nf] = *(const bf16x8*)&Ws[wc + nf * 16 + c16][g * 8];
#pragma unroll
        for (int mf = 0; mf < 4; mf++)
#pragma unroll
            for (int nf = 0; nf < 4; nf++)
                acc[mf][nf] = __builtin_amdgcn_mfma_f32_16x16x32_bf16(
                    af[mf], bfr[nf], acc[mf][nf], 0, 0, 0);
    }

    unsigned short* dst = which == 0 ? Qb : (which == 1 ? Kb : Vb);
    const float* bias = which == 0 ? bq : (which == 1 ? bk : bv);
    const float scale = which == 0 ? 0.180336889f : 1.0f;  // 0.125*log2(e) | 1

#pragma unroll
    for (int mf = 0; mf < 4; mf++) {
#pragma unroll
        for (int nf = 0; nf < 4; nf++) {
            const int n = n0 + wc + nf * 16 + c16;
            const int c = n & 1023;
            const int hh = c >> 6, dk = c & 63;
            const float bval = bias[c];
#pragma unroll
            for (int r = 0; r < 4; r++) {
                const int m = m0 + wr + mf * 16 + g * 4 + r;
                const int t = m >> 2, bb = m & 3;             // m = t*B + b
                dst[((size_t)(bb * H + hh) * T + t) * DK + dk] =
                    f2bf((acc[mf][nf][r] + bval) * scale);
            }
        }
    }
}

// ---------------------------------------------------------------------------
// Output projection, bf16x3 (unchanged R7/R11 passing structure).
// ---------------------------------------------------------------------------
__global__ __launch_bounds__(256) void oproj_gemm(
        const unsigned short* __restrict__ Xh, const unsigned short* __restrict__ Xl,
        const unsigned short* __restrict__ Wh, const unsigned short* __restrict__ Wl,
        const float* __restrict__ bo, float* __restrict__ out) {
    __shared__ __align__(16) unsigned short Ahs[128][32];
    __shared__ __align__(16) unsigned short Als[128][32];
    __shared__ __align__(16) unsigned short Bhs[128][32];
    __shared__ __align__(16) unsigned short Bls[128][32];

    const int tid = threadIdx.x;
    const int m0 = blockIdx.x * 128;
    const int n0 = blockIdx.y * 128;
    const int w = tid >> 6, lane = tid & 63;
    const int g = lane >> 4, c16 = lane & 15;
    const int wr = (w >> 1) * 64, wc = (w & 1) * 64;

    f32x4 acc[4][4] = {};

    for (int k0 = 0; k0 < C; k0 += 32) {
        __syncthreads();
#pragma unroll
        for (int half = 0; half < 2; half++) {
            const int chunk = tid + half * 256;
            const int r = chunk >> 2, s = chunk & 3;
            const size_t goffA = (size_t)(m0 + r) * C + k0 + s * 8;
            const size_t goffB = (size_t)(n0 + r) * C + k0 + s * 8;
            gload_lds16(Xh + goffA, (char*)&Ahs[0][0] + chunk * 16);
            gload_lds16(Xl + goffA, (char*)&Als[0][0] + chunk * 16);
            gload_lds16(Wh + goffB, (char*)&Bhs[0][0] + chunk * 16);
            gload_lds16(Wl + goffB, (char*)&Bls[0][0] + chunk * 16);
        }
        __syncthreads();

        bf16x8 ah[4], al[4];
#pragma unroll
        for (int mf = 0; mf < 4; mf++) {
            ah[mf] = *(const bf16x8*)&Ahs[wr + mf * 16 + c16][g * 8];
            al[mf] = *(const bf16x8*)&Als[wr + mf * 16 + c16][g * 8];
        }
#pragma unroll
        for (int nf = 0; nf < 4; nf++) {
            const bf16x8 wh = *(const bf16x8*)&Bhs[wc + nf * 16 + c16][g * 8];
            const bf16x8 wl = *(const bf16x8*)&Bls[wc + nf * 16 + c16][g * 8];
#pragma unroll
            for (int mf = 0; mf < 4; mf++) {
                acc[mf][nf] = __builtin_amdgcn_mfma_f32_16x16x32_bf16(ah[mf], wh, acc[mf][nf], 0, 0, 0);
                acc[mf][nf] = __builtin_amdgcn_mfma_f32_16x16x32_bf16(al[mf], wh, acc[mf][nf], 0, 0, 0);
                acc[mf][nf] = __builtin_amdgcn_mfma_f32_16x16x32_bf16(ah[mf], wl, acc[mf][nf], 0, 0, 0);
            }
        }
    }

#pragma unroll
    for (int mf = 0; mf < 4; mf++) {
#pragma unroll
        for (int nf = 0; nf < 4; nf++) {
            const int n = n0 + wc + nf * 16 + c16;
            const float bval = bo[n];
#pragma unroll
            for (int r = 0; r < 4; r++) {
                const int m = m0 + wr + mf * 16 + g * 4 + r;  // m = b*T + t
                const int t = m & 2047, bb = m >> 11;
                out[((size_t)t * B + bb) * C + n] = acc[mf][nf][r] + bval;
            }
        }
    }
}

// ---------------------------------------------------------------------------
// Flash attention v8 = R11 (passing, 144.5 us) + three local tweaks:
//  1. nib mask: nib = mbits>>(4g) once per tile; per-element test becomes a
//     compile-time-constant bit extract (identity transform).
//  2. rs reduction moved AFTER the PV MFMA cluster (same fp order, bit-
//     identical; DS shuffles now overlap MFMA).
//  3. s_setprio(1) brackets around QK^T and PV MFMA clusters (T5).
// ---------------------------------------------------------------------------
__global__ __launch_bounds__(256) void attn_mfma(const unsigned short* __restrict__ Q,
                                                 const unsigned short* __restrict__ K,
                                                 const unsigned short* __restrict__ V,
                                                 const int* __restrict__ mask,
                                                 unsigned short* __restrict__ Xh,
                                                 unsigned short* __restrict__ Xl) {
    __shared__ __align__(16) short Ks[2][64][72];   // 2 x 9216 B
    __shared__ __align__(16) short Vt[2][64][72];   // 2 x 9216 B (transposed V)
    __shared__ __align__(16) short Pl[4][16][72];   //     9216 B wave-private strips

    const int b = blockIdx.z, h = blockIdx.y;
    const int q0 = blockIdx.x * 128;
    const int tid = threadIdx.x;
    const int wl = tid >> 6;
    const int lane = tid & 63;
    const int g = lane >> 4;
    const int c16 = lane & 15;

    const size_t bh = (size_t)(b * H + h) * T * DK;
    const unsigned short* Qg = Q + bh;
    const unsigned short* Kg = K + bh;
    const unsigned short* Vg = V + bh;
    const int* mb = mask + b * T;

    bf16x8 qf[2][2];
#pragma unroll
    for (int qs = 0; qs < 2; qs++)
#pragma unroll
        for (int sl = 0; sl < 2; sl++)
            qf[qs][sl] = *(const bf16x8*)(Qg +
                (size_t)(q0 + wl * 32 + qs * 16 + c16) * DK + g * 8 + sl * 32);

    f32x4 o[2][4] = {};
    float lrow[2] = {0.0f, 0.0f};

    const int skr = tid >> 3;
    const int skc = (tid & 7) * 8;
    const int kp = tid & 31, dc = tid >> 5;
    uint4 kra, krb; u16x8 va, vb; int mw;

#define ISSUE(kv0)                                                              \
    do {                                                                        \
        kra = *(const uint4*)(Kg + (size_t)((kv0) + skr) * DK + skc);           \
        krb = *(const uint4*)(Kg + (size_t)((kv0) + skr + 32) * DK + skc);      \
        va  = *(const u16x8*)(Vg + (size_t)((kv0) + 2 * kp) * DK + dc * 8);     \
        vb  = *(const u16x8*)(Vg + (size_t)((kv0) + 2 * kp + 1) * DK + dc * 8); \
        mw  = mb[(kv0) + lane];                                                 \
    } while (0)

    ISSUE(0);

    for (int kt = 0; kt < NT; ++kt) {
        const int buf = kt & 1;

        const unsigned long long mbits = __ballot(mw != 0);
        *(uint4*)&Ks[buf][skr][skc] = kra;
        *(uint4*)&Ks[buf][skr + 32][skc] = krb;
#pragma unroll
        for (int j = 0; j < 8; j++) {
            *(uint32_t*)&Vt[buf][dc * 8 + j][2 * kp] =
                (uint32_t)(unsigned short)va[j] | ((uint32_t)(unsigned short)vb[j] << 16);
        }
        if (kt + 1 < NT) ISSUE((kt + 1) * 64);

        block_sync_lds();

        // per-lane mask nibbles: bit(16t + 4g + r) of mbits == bit((t&1)*16+r)
        // of (t<2 ? nlo : nhi), where nib = mbits >> 4g  (constant shifts!)
        const unsigned long long nib = mbits >> (4 * g);
        const uint32_t nlo = (uint32_t)nib;
        const uint32_t nhi = (uint32_t)(nib >> 32);

        bf16x8 kf[4][2], vf[4][2];
#pragma unroll
        for (int t = 0; t < 4; t++)
#pragma unroll
            for (int sl = 0; sl < 2; sl++) {
                kf[t][sl] = *(const bf16x8*)&Ks[buf][t * 16 + c16][g * 8 + sl * 32];
                vf[t][sl] = *(const bf16x8*)&Vt[buf][t * 16 + c16][g * 8 + sl * 32];
            }

#pragma unroll
        for (int qs = 0; qs < 2; qs++) {
            // ---- S^T tile ----
            f32x4 s4[4];
            __builtin_amdgcn_s_setprio(1);
#pragma unroll
            for (int t = 0; t < 4; t++) {
                f32x4 acc = {0.f, 0.f, 0.f, 0.f};
                acc = __builtin_amdgcn_mfma_f32_16x16x32_bf16(kf[t][0], qf[qs][0], acc, 0, 0, 0);
                acc = __builtin_amdgcn_mfma_f32_16x16x32_bf16(kf[t][1], qf[qs][1], acc, 0, 0, 0);
                s4[t] = acc;
            }
            __builtin_amdgcn_s_setprio(0);

            // ---- p = exp2(s'), zero masked (const-shift bit test) ----
#pragma unroll
            for (int t = 0; t < 4; t++) {
                const uint32_t sel = (t & 2) ? nhi : nlo;
#pragma unroll
                for (int r = 0; r < 4; r++) {
                    float p = __builtin_amdgcn_exp2f(s4[t][r]);
                    p = ((sel >> ((t & 1) * 16 + r)) & 1u) ? 0.0f : p;
                    s4[t][r] = p;
                }
            }

            // ---- P row -> wave-private LDS (cvt_pk b32) -> B-fragments ----
            cfence();
#pragma unroll
            for (int t = 0; t < 4; t++)
#pragma unroll
                for (int rr = 0; rr < 2; rr++) {
                    const uint32_t wv = cvtpk_bf16(s4[t][2 * rr], s4[t][2 * rr + 1]);
                    *(uint32_t*)&Pl[wl][c16][16 * t + 4 * g + 2 * rr] = wv;
                }
            cfence();
            bf16x8 pa[2];
            pa[0] = *(const bf16x8*)&Pl[wl][c16][g * 8];
            pa[1] = *(const bf16x8*)&Pl[wl][c16][g * 8 + 32];
            cfence();

            // ---- O^T += V^T P^T ----
            __builtin_amdgcn_s_setprio(1);
#pragma unroll
            for (int td = 0; td < 4; td++) {
                o[qs][td] = __builtin_amdgcn_mfma_f32_16x16x32_bf16(vf[td][0], pa[0], o[qs][td], 0, 0, 0);
                o[qs][td] = __builtin_amdgcn_mfma_f32_16x16x32_bf16(vf[td][1], pa[1], o[qs][td], 0, 0, 0);
            }
            __builtin_amdgcn_s_setprio(0);

            // ---- denominator (moved after PV; same fp order -> identical) ----
            float rs = 0.0f;
#pragma unroll
            for (int t = 0; t < 4; t++)
#pragma unroll
                for (int r = 0; r < 4; r++) rs += s4[t][r];
            rs += __shfl_xor(rs, 16);
            rs += __shfl_xor(rs, 32);
            lrow[qs] += rs;
        }
    }
#undef ISSUE

#pragma unroll
    for (int qs = 0; qs < 2; qs++) {
        const float inv = 1.0f / lrow[qs];
        const int qq = q0 + wl * 32 + qs * 16 + c16;
#pragma unroll
        for (int td = 0; td < 4; td++) {
            u16x4 hi4, lo4;
#pragma unroll
            for (int r = 0; r < 4; r++) {
                const float val = o[qs][td][r] * inv;
                const unsigned short hv = f2bf(val);
                hi4[r] = hv;
                lo4[r] = f2bf(val - bf2f(hv));
            }
            const size_t idx = ((size_t)b * T + qq) * C + h * DK + td * 16 + 4 * g;
            *(u16x4*)(Xh + idx) = hi4;
            *(u16x4*)(Xl + idx) = lo4;
        }
    }
}

// ---------------------------------------------------------------------------
extern "C" void kernel_launch(void* const* d_in, const int* in_sizes, int n_in,
                              void* d_out, int out_size, void* d_ws, size_t ws_size,
                              hipStream_t stream) {
    const float* query = (const float*)d_in[0];
    const float* key   = (const float*)d_in[1];
    const float* value = (const float*)d_in[2];
    const int*   kpm   = (const int*)d_in[3];
    const float* Wq = (const float*)d_in[4];
    const float* bq = (const float*)d_in[5];
    const float* Wk = (const float*)d_in[6];
    const float* bk = (const float*)d_in[7];
    const float* Wv = (const float*)d_in[8];
    const float* bv = (const float*)d_in[9];
    const float* Wo = (const float*)d_in[10];
    const float* bo = (const float*)d_in[11];

    constexpr size_t MB = 1u << 20;
    char* w8 = (char*)d_ws;
    unsigned short* XhB = (unsigned short*)(w8 + 0 * MB);
    unsigned short* XlB = (unsigned short*)(w8 + 16 * MB);
    unsigned short* WB  = (unsigned short*)(w8 + 48 * MB);
    unsigned short* WoH = (unsigned short*)(w8 + 54 * MB);
    unsigned short* WoL = (unsigned short*)(w8 + 56 * MB);
    unsigned short* Qb  = (unsigned short*)(w8 + 64 * MB);
    unsigned short* Kb  = (unsigned short*)(w8 + 80 * MB);
    unsigned short* Vb  = (unsigned short*)(w8 + 96 * MB);

    const dim3 blk(256);

    convert_w<<<dim3(512, 3), blk, 0, stream>>>(Wq, Wk, Wv, WB);
    convert_wo<<<dim3(512, 1), blk, 0, stream>>>(Wo, WoH, WoL);

    qkv_gemm<<<dim3(M / 128, 3 * C / 128), blk, 0, stream>>>(query, key, value,
                                                             WB, bq, bk, bv,
                                                             Qb, Kb, Vb);

    attn_mfma<<<dim3(T / 128, H, B), blk, 0, stream>>>(Qb, Kb, Vb, kpm, XhB, XlB);

    oproj_gemm<<<dim3(M / 128, C / 128), blk, 0, stream>>>(XhB, XlB, WoH, WoL,
                                                           bo, (float*)d_out);
}

// Round 15
// 276.487 us; speedup vs baseline: 1.1671x; 1.1671x over previous
//
#include <hip/hip_runtime.h>
#include <hip/hip_bf16.h>
#include <cstddef>
#include <cstdint>

constexpr int T  = 2048;
constexpr int B  = 4;
constexpr int C  = 1024;
constexpr int H  = 16;
constexpr int DK = 64;
constexpr int M  = T * B;   // 8192
constexpr int NT = T / 64;  // 32 KV tiles

typedef __attribute__((ext_vector_type(8))) short bf16x8;
typedef __attribute__((ext_vector_type(4))) float f32x4;
typedef __attribute__((ext_vector_type(4))) unsigned short u16x4;
typedef __attribute__((ext_vector_type(8))) unsigned short u16x8;

__device__ inline unsigned short f2bf(float f) {
    union { float f; uint32_t u; } v; v.f = f;
    uint32_t u = v.u + 0x7fff + ((v.u >> 16) & 1);  // RNE
    return (unsigned short)(u >> 16);
}
__device__ inline float bf2f(unsigned short h) {
    union { uint32_t u; float f; } v; v.u = (uint32_t)h << 16;
    return v.f;
}
// HW packed f32->bf16 pair (no builtin on gfx950; T12 recipe)
__device__ inline uint32_t cvtpk_bf16(float lo, float hi) {
    uint32_t r;
    asm("v_cvt_pk_bf16_f32 %0, %1, %2" : "=v"(r) : "v"(lo), "v"(hi));
    return r;
}
// compiler-level full memory fence (no instruction emitted)
__device__ inline void cfence() { asm volatile("" ::: "memory"); }

// Raw workgroup barrier WITHOUT the vmcnt(0) drain __syncthreads emits.
__device__ inline void block_sync_lds() {
    __builtin_amdgcn_sched_barrier(0);
    asm volatile("s_waitcnt lgkmcnt(0)" ::: "memory");
    __builtin_amdgcn_sched_barrier(0);
    __builtin_amdgcn_s_barrier();
    __builtin_amdgcn_sched_barrier(0);
}

// global -> LDS direct DMA, 16B per lane.
__device__ inline void gload_lds16(const void* g, void* l) {
    auto gp = reinterpret_cast<const __attribute__((address_space(1))) char*>(
        reinterpret_cast<uintptr_t>(g));
    auto lp = reinterpret_cast<__attribute__((address_space(3))) char*>(
        reinterpret_cast<uintptr_t>(l));
    __builtin_amdgcn_global_load_lds(gp, lp, 16, 0, 0);
}

// ---------------------------------------------------------------------------
// Converters (memory-bound) — convert_in RESTORED (R14's fp32-fused qkv lost
// 100 us to staging-write bank conflicts + fp32 A traffic; bf16 A + gload_lds
// is the proven structure).
// ---------------------------------------------------------------------------
__global__ __launch_bounds__(256) void convert_in(const float* __restrict__ q,
                                                  const float* __restrict__ k,
                                                  const float* __restrict__ v,
                                                  unsigned short* __restrict__ dq,
                                                  unsigned short* __restrict__ dk2,
                                                  unsigned short* __restrict__ dv) {
    const float* s; unsigned short* d;
    if (blockIdx.y == 0) { s = q; d = dq; }
    else if (blockIdx.y == 1) { s = k; d = dk2; }
    else { s = v; d = dv; }
    const size_t i = ((size_t)blockIdx.x * 256 + threadIdx.x) * 8;
    const float4 a = *(const float4*)(s + i);
    const float4 b = *(const float4*)(s + i + 4);
    u16x8 o;
    o[0] = f2bf(a.x); o[1] = f2bf(a.y); o[2] = f2bf(a.z); o[3] = f2bf(a.w);
    o[4] = f2bf(b.x); o[5] = f2bf(b.y); o[6] = f2bf(b.z); o[7] = f2bf(b.w);
    *(u16x8*)(d + i) = o;
}

__global__ __launch_bounds__(256) void convert_w(const float* __restrict__ wq,
                                                 const float* __restrict__ wk,
                                                 const float* __restrict__ wv,
                                                 unsigned short* __restrict__ dst) {
    const float* s = blockIdx.y == 0 ? wq : (blockIdx.y == 1 ? wk : wv);
    unsigned short* d = dst + (size_t)blockIdx.y * C * C;
    const size_t i = ((size_t)blockIdx.x * 256 + threadIdx.x) * 8;
    const float4 a = *(const float4*)(s + i);
    const float4 b = *(const float4*)(s + i + 4);
    u16x8 o;
    o[0] = f2bf(a.x); o[1] = f2bf(a.y); o[2] = f2bf(a.z); o[3] = f2bf(a.w);
    o[4] = f2bf(b.x); o[5] = f2bf(b.y); o[6] = f2bf(b.z); o[7] = f2bf(b.w);
    *(u16x8*)(d + i) = o;
}

__global__ __launch_bounds__(256) void convert_wo(const float* __restrict__ wo,
                                                  unsigned short* __restrict__ hi,
                                                  unsigned short* __restrict__ lo) {
    const size_t i = ((size_t)blockIdx.x * 256 + threadIdx.x) * 8;
#pragma unroll
    for (int j = 0; j < 8; j++) {
        const float x = wo[i + j];
        const unsigned short h = f2bf(x);
        hi[i + j] = h;
        lo[i + j] = f2bf(x - bf2f(h));
    }
}

// ---------------------------------------------------------------------------
// Fused QKV projection GEMM — R11-exact (proven ~60 us): bf16 A, gload_lds
// staging, two __syncthreads per K-step.
// Q scale folds 1/sqrt(DK) * log2(e) for the exp2-based softmax.
// ---------------------------------------------------------------------------
__global__ __launch_bounds__(256) void qkv_gemm(
        const unsigned short* __restrict__ Aq,
        const unsigned short* __restrict__ Ak,
        const unsigned short* __restrict__ Av,
        const unsigned short* __restrict__ W,
        const float* __restrict__ bq, const float* __restrict__ bk,
        const float* __restrict__ bv,
        unsigned short* __restrict__ Qb, unsigned short* __restrict__ Kb,
        unsigned short* __restrict__ Vb) {
    __shared__ __align__(16) unsigned short As[128][32];
    __shared__ __align__(16) unsigned short Ws[128][32];

    const int tid = threadIdx.x;
    const int m0 = blockIdx.x * 128;
    const int n0 = blockIdx.y * 128;
    const int w = tid >> 6, lane = tid & 63;
    const int g = lane >> 4, c16 = lane & 15;
    const int wr = (w >> 1) * 64, wc = (w & 1) * 64;

    const int which = n0 >> 10;  // 0=Q 1=K 2=V (no straddle)
    const unsigned short* A = which == 0 ? Aq : (which == 1 ? Ak : Av);

    f32x4 acc[4][4] = {};

    for (int k0 = 0; k0 < C; k0 += 32) {
        __syncthreads();
#pragma unroll
        for (int half = 0; half < 2; half++) {
            const int chunk = tid + half * 256;       // 0..511
            const int r = chunk >> 2, s = chunk & 3;  // row, 16B slot
            gload_lds16(A + (size_t)(m0 + r) * C + k0 + s * 8,
                        (char*)&As[0][0] + chunk * 16);
            gload_lds16(W + (size_t)(n0 + r) * C + k0 + s * 8,
                        (char*)&Ws[0][0] + chunk * 16);
        }
        __syncthreads();

        bf16x8 af[4], bfr[4];
#pragma unroll
        for (int mf = 0; mf < 4; mf++)
            af[mf] = *(const bf16x8*)&As[wr + mf * 16 + c16][g * 8];
#pragma unroll
        for (int nf = 0; nf < 4; nf++)
            bfr[nf] = *(const bf16x8*)&Ws[wc + nf * 16 + c16][g * 8];
#pragma unroll
        for (int mf = 0; mf < 4; mf++)
#pragma unroll
            for (int nf = 0; nf < 4; nf++)
                acc[mf][nf] = __builtin_amdgcn_mfma_f32_16x16x32_bf16(
                    af[mf], bfr[nf], acc[mf][nf], 0, 0, 0);
    }

    unsigned short* dst = which == 0 ? Qb : (which == 1 ? Kb : Vb);
    const float* bias = which == 0 ? bq : (which == 1 ? bk : bv);
    const float scale = which == 0 ? 0.180336889f : 1.0f;  // 0.125*log2(e) | 1

#pragma unroll
    for (int mf = 0; mf < 4; mf++) {
#pragma unroll
        for (int nf = 0; nf < 4; nf++) {
            const int n = n0 + wc + nf * 16 + c16;
            const int c = n & 1023;
            const int hh = c >> 6, dk = c & 63;
            const float bval = bias[c];
#pragma unroll
            for (int r = 0; r < 4; r++) {
                const int m = m0 + wr + mf * 16 + g * 4 + r;
                const int t = m >> 2, bb = m & 3;             // m = t*B + b
                dst[((size_t)(bb * H + hh) * T + t) * DK + dk] =
                    f2bf((acc[mf][nf][r] + bval) * scale);
            }
        }
    }
}

// ---------------------------------------------------------------------------
// Output projection, bf16x3 (unchanged R7/R11 passing structure).
// ---------------------------------------------------------------------------
__global__ __launch_bounds__(256) void oproj_gemm(
        const unsigned short* __restrict__ Xh, const unsigned short* __restrict__ Xl,
        const unsigned short* __restrict__ Wh, const unsigned short* __restrict__ Wl,
        const float* __restrict__ bo, float* __restrict__ out) {
    __shared__ __align__(16) unsigned short Ahs[128][32];
    __shared__ __align__(16) unsigned short Als[128][32];
    __shared__ __align__(16) unsigned short Bhs[128][32];
    __shared__ __align__(16) unsigned short Bls[128][32];

    const int tid = threadIdx.x;
    const int m0 = blockIdx.x * 128;
    const int n0 = blockIdx.y * 128;
    const int w = tid >> 6, lane = tid & 63;
    const int g = lane >> 4, c16 = lane & 15;
    const int wr = (w >> 1) * 64, wc = (w & 1) * 64;

    f32x4 acc[4][4] = {};

    for (int k0 = 0; k0 < C; k0 += 32) {
        __syncthreads();
#pragma unroll
        for (int half = 0; half < 2; half++) {
            const int chunk = tid + half * 256;
            const int r = chunk >> 2, s = chunk & 3;
            const size_t goffA = (size_t)(m0 + r) * C + k0 + s * 8;
            const size_t goffB = (size_t)(n0 + r) * C + k0 + s * 8;
            gload_lds16(Xh + goffA, (char*)&Ahs[0][0] + chunk * 16);
            gload_lds16(Xl + goffA, (char*)&Als[0][0] + chunk * 16);
            gload_lds16(Wh + goffB, (char*)&Bhs[0][0] + chunk * 16);
            gload_lds16(Wl + goffB, (char*)&Bls[0][0] + chunk * 16);
        }
        __syncthreads();

        bf16x8 ah[4], al[4];
#pragma unroll
        for (int mf = 0; mf < 4; mf++) {
            ah[mf] = *(const bf16x8*)&Ahs[wr + mf * 16 + c16][g * 8];
            al[mf] = *(const bf16x8*)&Als[wr + mf * 16 + c16][g * 8];
        }
#pragma unroll
        for (int nf = 0; nf < 4; nf++) {
            const bf16x8 wh = *(const bf16x8*)&Bhs[wc + nf * 16 + c16][g * 8];
            const bf16x8 wl = *(const bf16x8*)&Bls[wc + nf * 16 + c16][g * 8];
#pragma unroll
            for (int mf = 0; mf < 4; mf++) {
                acc[mf][nf] = __builtin_amdgcn_mfma_f32_16x16x32_bf16(ah[mf], wh, acc[mf][nf], 0, 0, 0);
                acc[mf][nf] = __builtin_amdgcn_mfma_f32_16x16x32_bf16(al[mf], wh, acc[mf][nf], 0, 0, 0);
                acc[mf][nf] = __builtin_amdgcn_mfma_f32_16x16x32_bf16(ah[mf], wl, acc[mf][nf], 0, 0, 0);
            }
        }
    }

#pragma unroll
    for (int mf = 0; mf < 4; mf++) {
#pragma unroll
        for (int nf = 0; nf < 4; nf++) {
            const int n = n0 + wc + nf * 16 + c16;
            const float bval = bo[n];
#pragma unroll
            for (int r = 0; r < 4; r++) {
                const int m = m0 + wr + mf * 16 + g * 4 + r;  // m = b*T + t
                const int t = m & 2047, bb = m >> 11;
                out[((size_t)t * B + bb) * C + n] = acc[mf][nf][r] + bval;
            }
        }
    }
}

// ---------------------------------------------------------------------------
// Flash attention v8 (from R14, now measurable in isolation): R11 structure +
//  1. nib mask (const-shift bit extracts), 2. rs after PV, 3. s_setprio.
// ---------------------------------------------------------------------------
__global__ __launch_bounds__(256) void attn_mfma(const unsigned short* __restrict__ Q,
                                                 const unsigned short* __restrict__ K,
                                                 const unsigned short* __restrict__ V,
                                                 const int* __restrict__ mask,
                                                 unsigned short* __restrict__ Xh,
                                                 unsigned short* __restrict__ Xl) {
    __shared__ __align__(16) short Ks[2][64][72];   // 2 x 9216 B
    __shared__ __align__(16) short Vt[2][64][72];   // 2 x 9216 B (transposed V)
    __shared__ __align__(16) short Pl[4][16][72];   //     9216 B wave-private strips

    const int b = blockIdx.z, h = blockIdx.y;
    const int q0 = blockIdx.x * 128;
    const int tid = threadIdx.x;
    const int wl = tid >> 6;
    const int lane = tid & 63;
    const int g = lane >> 4;
    const int c16 = lane & 15;

    const size_t bh = (size_t)(b * H + h) * T * DK;
    const unsigned short* Qg = Q + bh;
    const unsigned short* Kg = K + bh;
    const unsigned short* Vg = V + bh;
    const int* mb = mask + b * T;

    bf16x8 qf[2][2];
#pragma unroll
    for (int qs = 0; qs < 2; qs++)
#pragma unroll
        for (int sl = 0; sl < 2; sl++)
            qf[qs][sl] = *(const bf16x8*)(Qg +
                (size_t)(q0 + wl * 32 + qs * 16 + c16) * DK + g * 8 + sl * 32);

    f32x4 o[2][4] = {};
    float lrow[2] = {0.0f, 0.0f};

    const int skr = tid >> 3;
    const int skc = (tid & 7) * 8;
    const int kp = tid & 31, dc = tid >> 5;
    uint4 kra, krb; u16x8 va, vb; int mw;

#define ISSUE(kv0)                                                              \
    do {                                                                        \
        kra = *(const uint4*)(Kg + (size_t)((kv0) + skr) * DK + skc);           \
        krb = *(const uint4*)(Kg + (size_t)((kv0) + skr + 32) * DK + skc);      \
        va  = *(const u16x8*)(Vg + (size_t)((kv0) + 2 * kp) * DK + dc * 8);     \
        vb  = *(const u16x8*)(Vg + (size_t)((kv0) + 2 * kp + 1) * DK + dc * 8); \
        mw  = mb[(kv0) + lane];                                                 \
    } while (0)

    ISSUE(0);

    for (int kt = 0; kt < NT; ++kt) {
        const int buf = kt & 1;

        const unsigned long long mbits = __ballot(mw != 0);
        *(uint4*)&Ks[buf][skr][skc] = kra;
        *(uint4*)&Ks[buf][skr + 32][skc] = krb;
#pragma unroll
        for (int j = 0; j < 8; j++) {
            *(uint32_t*)&Vt[buf][dc * 8 + j][2 * kp] =
                (uint32_t)(unsigned short)va[j] | ((uint32_t)(unsigned short)vb[j] << 16);
        }
        if (kt + 1 < NT) ISSUE((kt + 1) * 64);

        block_sync_lds();

        // per-lane mask nibbles: bit(16t + 4g + r) of mbits == bit((t&1)*16+r)
        // of (t<2 ? nlo : nhi), where nib = mbits >> 4g
        const unsigned long long nib = mbits >> (4 * g);
        const uint32_t nlo = (uint32_t)nib;
        const uint32_t nhi = (uint32_t)(nib >> 32);

        bf16x8 kf[4][2], vf[4][2];
#pragma unroll
        for (int t = 0; t < 4; t++)
#pragma unroll
            for (int sl = 0; sl < 2; sl++) {
                kf[t][sl] = *(const bf16x8*)&Ks[buf][t * 16 + c16][g * 8 + sl * 32];
                vf[t][sl] = *(const bf16x8*)&Vt[buf][t * 16 + c16][g * 8 + sl * 32];
            }

#pragma unroll
        for (int qs = 0; qs < 2; qs++) {
            // ---- S^T tile ----
            f32x4 s4[4];
            __builtin_amdgcn_s_setprio(1);
#pragma unroll
            for (int t = 0; t < 4; t++) {
                f32x4 acc = {0.f, 0.f, 0.f, 0.f};
                acc = __builtin_amdgcn_mfma_f32_16x16x32_bf16(kf[t][0], qf[qs][0], acc, 0, 0, 0);
                acc = __builtin_amdgcn_mfma_f32_16x16x32_bf16(kf[t][1], qf[qs][1], acc, 0, 0, 0);
                s4[t] = acc;
            }
            __builtin_amdgcn_s_setprio(0);

            // ---- p = exp2(s'), zero masked (const-shift bit test) ----
#pragma unroll
            for (int t = 0; t < 4; t++) {
                const uint32_t sel = (t & 2) ? nhi : nlo;
#pragma unroll
                for (int r = 0; r < 4; r++) {
                    float p = __builtin_amdgcn_exp2f(s4[t][r]);
                    p = ((sel >> ((t & 1) * 16 + r)) & 1u) ? 0.0f : p;
                    s4[t][r] = p;
                }
            }

            // ---- P row -> wave-private LDS (cvt_pk b32) -> B-fragments ----
            cfence();
#pragma unroll
            for (int t = 0; t < 4; t++)
#pragma unroll
                for (int rr = 0; rr < 2; rr++) {
                    const uint32_t wv = cvtpk_bf16(s4[t][2 * rr], s4[t][2 * rr + 1]);
                    *(uint32_t*)&Pl[wl][c16][16 * t + 4 * g + 2 * rr] = wv;
                }
            cfence();
            bf16x8 pa[2];
            pa[0] = *(const bf16x8*)&Pl[wl][c16][g * 8];
            pa[1] = *(const bf16x8*)&Pl[wl][c16][g * 8 + 32];
            cfence();

            // ---- O^T += V^T P^T ----
            __builtin_amdgcn_s_setprio(1);
#pragma unroll
            for (int td = 0; td < 4; td++) {
                o[qs][td] = __builtin_amdgcn_mfma_f32_16x16x32_bf16(vf[td][0], pa[0], o[qs][td], 0, 0, 0);
                o[qs][td] = __builtin_amdgcn_mfma_f32_16x16x32_bf16(vf[td][1], pa[1], o[qs][td], 0, 0, 0);
            }
            __builtin_amdgcn_s_setprio(0);

            // ---- denominator (after PV; same fp order -> identical) ----
            float rs = 0.0f;
#pragma unroll
            for (int t = 0; t < 4; t++)
#pragma unroll
                for (int r = 0; r < 4; r++) rs += s4[t][r];
            rs += __shfl_xor(rs, 16);
            rs += __shfl_xor(rs, 32);
            lrow[qs] += rs;
        }
    }
#undef ISSUE

#pragma unroll
    for (int qs = 0; qs < 2; qs++) {
        const float inv = 1.0f / lrow[qs];
        const int qq = q0 + wl * 32 + qs * 16 + c16;
#pragma unroll
        for (int td = 0; td < 4; td++) {
            u16x4 hi4, lo4;
#pragma unroll
            for (int r = 0; r < 4; r++) {
                const float val = o[qs][td][r] * inv;
                const unsigned short hv = f2bf(val);
                hi4[r] = hv;
                lo4[r] = f2bf(val - bf2f(hv));
            }
            const size_t idx = ((size_t)b * T + qq) * C + h * DK + td * 16 + 4 * g;
            *(u16x4*)(Xh + idx) = hi4;
            *(u16x4*)(Xl + idx) = lo4;
        }
    }
}

// ---------------------------------------------------------------------------
extern "C" void kernel_launch(void* const* d_in, const int* in_sizes, int n_in,
                              void* d_out, int out_size, void* d_ws, size_t ws_size,
                              hipStream_t stream) {
    const float* query = (const float*)d_in[0];
    const float* key   = (const float*)d_in[1];
    const float* value = (const float*)d_in[2];
    const int*   kpm   = (const int*)d_in[3];
    const float* Wq = (const float*)d_in[4];
    const float* bq = (const float*)d_in[5];
    const float* Wk = (const float*)d_in[6];
    const float* bk = (const float*)d_in[7];
    const float* Wv = (const float*)d_in[8];
    const float* bv = (const float*)d_in[9];
    const float* Wo = (const float*)d_in[10];
    const float* bo = (const float*)d_in[11];

    constexpr size_t MB = 1u << 20;
    char* w8 = (char*)d_ws;
    unsigned short* Qa  = (unsigned short*)(w8 + 0 * MB);   // reused as Xh
    unsigned short* Ka  = (unsigned short*)(w8 + 16 * MB);  // reused as Xl
    unsigned short* Va  = (unsigned short*)(w8 + 32 * MB);
    unsigned short* WB  = (unsigned short*)(w8 + 48 * MB);
    unsigned short* WoH = (unsigned short*)(w8 + 54 * MB);
    unsigned short* WoL = (unsigned short*)(w8 + 56 * MB);
    unsigned short* Qb  = (unsigned short*)(w8 + 64 * MB);
    unsigned short* Kb  = (unsigned short*)(w8 + 80 * MB);
    unsigned short* Vb  = (unsigned short*)(w8 + 96 * MB);
    unsigned short* XhB = Qa;
    unsigned short* XlB = Ka;

    const dim3 blk(256);

    convert_in<<<dim3(4096, 3), blk, 0, stream>>>(query, key, value, Qa, Ka, Va);
    convert_w<<<dim3(512, 3), blk, 0, stream>>>(Wq, Wk, Wv, WB);
    convert_wo<<<dim3(512, 1), blk, 0, stream>>>(Wo, WoH, WoL);

    qkv_gemm<<<dim3(M / 128, 3 * C / 128), blk, 0, stream>>>(Qa, Ka, Va, WB,
                                                             bq, bk, bv,
                                                             Qb, Kb, Vb);

    attn_mfma<<<dim3(T / 128, H, B), blk, 0, stream>>>(Qb, Kb, Vb, kpm, XhB, XlB);

    oproj_gemm<<<dim3(M / 128, C / 128), blk, 0, stream>>>(XhB, XlB, WoH, WoL,
                                                           bo, (float*)d_out);
}

// Round 16
// 276.413 us; speedup vs baseline: 1.1675x; 1.0003x over previous
//
#include <hip/hip_runtime.h>
#include <hip/hip_bf16.h>
#include <cstddef>
#include <cstdint>

constexpr int T  = 2048;
constexpr int B  = 4;
constexpr int C  = 1024;
constexpr int H  = 16;
constexpr int DK = 64;
constexpr int M  = T * B;   // 8192
constexpr int NT = T / 64;  // 32 KV tiles

typedef __attribute__((ext_vector_type(8))) short bf16x8;
typedef __attribute__((ext_vector_type(4))) float f32x4;
typedef __attribute__((ext_vector_type(4))) unsigned short u16x4;
typedef __attribute__((ext_vector_type(8))) unsigned short u16x8;

__device__ inline unsigned short f2bf(float f) {
    union { float f; uint32_t u; } v; v.f = f;
    uint32_t u = v.u + 0x7fff + ((v.u >> 16) & 1);  // RNE
    return (unsigned short)(u >> 16);
}
__device__ inline float bf2f(unsigned short h) {
    union { uint32_t u; float f; } v; v.u = (uint32_t)h << 16;
    return v.f;
}
// HW packed f32->bf16 pair (no builtin on gfx950; T12 recipe)
__device__ inline uint32_t cvtpk_bf16(float lo, float hi) {
    uint32_t r;
    asm("v_cvt_pk_bf16_f32 %0, %1, %2" : "=v"(r) : "v"(lo), "v"(hi));
    return r;
}
// compiler-level full memory fence (no instruction emitted)
__device__ inline void cfence() { asm volatile("" ::: "memory"); }

// Raw workgroup barrier WITHOUT the vmcnt(0) drain __syncthreads emits.
__device__ inline void block_sync_lds() {
    __builtin_amdgcn_sched_barrier(0);
    asm volatile("s_waitcnt lgkmcnt(0)" ::: "memory");
    __builtin_amdgcn_sched_barrier(0);
    __builtin_amdgcn_s_barrier();
    __builtin_amdgcn_sched_barrier(0);
}

// global -> LDS direct DMA, 16B per lane.
__device__ inline void gload_lds16(const void* g, void* l) {
    auto gp = reinterpret_cast<const __attribute__((address_space(1))) char*>(
        reinterpret_cast<uintptr_t>(g));
    auto lp = reinterpret_cast<__attribute__((address_space(3))) char*>(
        reinterpret_cast<uintptr_t>(l));
    __builtin_amdgcn_global_load_lds(gp, lp, 16, 0, 0);
}

// ---------------------------------------------------------------------------
// Converters (memory-bound, at HBM floor) — unchanged from R11.
// ---------------------------------------------------------------------------
__global__ __launch_bounds__(256) void convert_in(const float* __restrict__ q,
                                                  const float* __restrict__ k,
                                                  const float* __restrict__ v,
                                                  unsigned short* __restrict__ dq,
                                                  unsigned short* __restrict__ dk2,
                                                  unsigned short* __restrict__ dv) {
    const float* s; unsigned short* d;
    if (blockIdx.y == 0) { s = q; d = dq; }
    else if (blockIdx.y == 1) { s = k; d = dk2; }
    else { s = v; d = dv; }
    const size_t i = ((size_t)blockIdx.x * 256 + threadIdx.x) * 8;
    const float4 a = *(const float4*)(s + i);
    const float4 b = *(const float4*)(s + i + 4);
    u16x8 o;
    o[0] = f2bf(a.x); o[1] = f2bf(a.y); o[2] = f2bf(a.z); o[3] = f2bf(a.w);
    o[4] = f2bf(b.x); o[5] = f2bf(b.y); o[6] = f2bf(b.z); o[7] = f2bf(b.w);
    *(u16x8*)(d + i) = o;
}

__global__ __launch_bounds__(256) void convert_w(const float* __restrict__ wq,
                                                 const float* __restrict__ wk,
                                                 const float* __restrict__ wv,
                                                 unsigned short* __restrict__ dst) {
    const float* s = blockIdx.y == 0 ? wq : (blockIdx.y == 1 ? wk : wv);
    unsigned short* d = dst + (size_t)blockIdx.y * C * C;
    const size_t i = ((size_t)blockIdx.x * 256 + threadIdx.x) * 8;
    const float4 a = *(const float4*)(s + i);
    const float4 b = *(const float4*)(s + i + 4);
    u16x8 o;
    o[0] = f2bf(a.x); o[1] = f2bf(a.y); o[2] = f2bf(a.z); o[3] = f2bf(a.w);
    o[4] = f2bf(b.x); o[5] = f2bf(b.y); o[6] = f2bf(b.z); o[7] = f2bf(b.w);
    *(u16x8*)(d + i) = o;
}

__global__ __launch_bounds__(256) void convert_wo(const float* __restrict__ wo,
                                                  unsigned short* __restrict__ hi,
                                                  unsigned short* __restrict__ lo) {
    const size_t i = ((size_t)blockIdx.x * 256 + threadIdx.x) * 8;
#pragma unroll
    for (int j = 0; j < 8; j++) {
        const float x = wo[i + j];
        const unsigned short h = f2bf(x);
        hi[i + j] = h;
        lo[i + j] = f2bf(x - bf2f(h));
    }
}

// ---------------------------------------------------------------------------
// Fused QKV projection GEMM — R11-exact (at m97-structure ceiling ~900 TF).
// ---------------------------------------------------------------------------
__global__ __launch_bounds__(256) void qkv_gemm(
        const unsigned short* __restrict__ Aq,
        const unsigned short* __restrict__ Ak,
        const unsigned short* __restrict__ Av,
        const unsigned short* __restrict__ W,
        const float* __restrict__ bq, const float* __restrict__ bk,
        const float* __restrict__ bv,
        unsigned short* __restrict__ Qb, unsigned short* __restrict__ Kb,
        unsigned short* __restrict__ Vb) {
    __shared__ __align__(16) unsigned short As[128][32];
    __shared__ __align__(16) unsigned short Ws[128][32];

    const int tid = threadIdx.x;
    const int m0 = blockIdx.x * 128;
    const int n0 = blockIdx.y * 128;
    const int w = tid >> 6, lane = tid & 63;
    const int g = lane >> 4, c16 = lane & 15;
    const int wr = (w >> 1) * 64, wc = (w & 1) * 64;

    const int which = n0 >> 10;  // 0=Q 1=K 2=V (no straddle)
    const unsigned short* A = which == 0 ? Aq : (which == 1 ? Ak : Av);

    f32x4 acc[4][4] = {};

    for (int k0 = 0; k0 < C; k0 += 32) {
        __syncthreads();
#pragma unroll
        for (int half = 0; half < 2; half++) {
            const int chunk = tid + half * 256;       // 0..511
            const int r = chunk >> 2, s = chunk & 3;  // row, 16B slot
            gload_lds16(A + (size_t)(m0 + r) * C + k0 + s * 8,
                        (char*)&As[0][0] + chunk * 16);
            gload_lds16(W + (size_t)(n0 + r) * C + k0 + s * 8,
                        (char*)&Ws[0][0] + chunk * 16);
        }
        __syncthreads();

        bf16x8 af[4], bfr[4];
#pragma unroll
        for (int mf = 0; mf < 4; mf++)
            af[mf] = *(const bf16x8*)&As[wr + mf * 16 + c16][g * 8];
#pragma unroll
        for (int nf = 0; nf < 4; nf++)
            bfr[nf] = *(const bf16x8*)&Ws[wc + nf * 16 + c16][g * 8];
#pragma unroll
        for (int mf = 0; mf < 4; mf++)
#pragma unroll
            for (int nf = 0; nf < 4; nf++)
                acc[mf][nf] = __builtin_amdgcn_mfma_f32_16x16x32_bf16(
                    af[mf], bfr[nf], acc[mf][nf], 0, 0, 0);
    }

    unsigned short* dst = which == 0 ? Qb : (which == 1 ? Kb : Vb);
    const float* bias = which == 0 ? bq : (which == 1 ? bk : bv);
    const float scale = which == 0 ? 0.180336889f : 1.0f;  // 0.125*log2(e) | 1

#pragma unroll
    for (int mf = 0; mf < 4; mf++) {
#pragma unroll
        for (int nf = 0; nf < 4; nf++) {
            const int n = n0 + wc + nf * 16 + c16;
            const int c = n & 1023;
            const int hh = c >> 6, dk = c & 63;
            const float bval = bias[c];
#pragma unroll
            for (int r = 0; r < 4; r++) {
                const int m = m0 + wr + mf * 16 + g * 4 + r;
                const int t = m >> 2, bb = m & 3;             // m = t*B + b
                dst[((size_t)(bb * H + hh) * T + t) * DK + dk] =
                    f2bf((acc[mf][nf][r] + bval) * scale);
            }
        }
    }
}

// ---------------------------------------------------------------------------
// Output projection, bf16x3 (unchanged R7/R11 passing structure).
// ---------------------------------------------------------------------------
__global__ __launch_bounds__(256) void oproj_gemm(
        const unsigned short* __restrict__ Xh, const unsigned short* __restrict__ Xl,
        const unsigned short* __restrict__ Wh, const unsigned short* __restrict__ Wl,
        const float* __restrict__ bo, float* __restrict__ out) {
    __shared__ __align__(16) unsigned short Ahs[128][32];
    __shared__ __align__(16) unsigned short Als[128][32];
    __shared__ __align__(16) unsigned short Bhs[128][32];
    __shared__ __align__(16) unsigned short Bls[128][32];

    const int tid = threadIdx.x;
    const int m0 = blockIdx.x * 128;
    const int n0 = blockIdx.y * 128;
    const int w = tid >> 6, lane = tid & 63;
    const int g = lane >> 4, c16 = lane & 15;
    const int wr = (w >> 1) * 64, wc = (w & 1) * 64;

    f32x4 acc[4][4] = {};

    for (int k0 = 0; k0 < C; k0 += 32) {
        __syncthreads();
#pragma unroll
        for (int half = 0; half < 2; half++) {
            const int chunk = tid + half * 256;
            const int r = chunk >> 2, s = chunk & 3;
            const size_t goffA = (size_t)(m0 + r) * C + k0 + s * 8;
            const size_t goffB = (size_t)(n0 + r) * C + k0 + s * 8;
            gload_lds16(Xh + goffA, (char*)&Ahs[0][0] + chunk * 16);
            gload_lds16(Xl + goffA, (char*)&Als[0][0] + chunk * 16);
            gload_lds16(Wh + goffB, (char*)&Bhs[0][0] + chunk * 16);
            gload_lds16(Wl + goffB, (char*)&Bls[0][0] + chunk * 16);
        }
        __syncthreads();

        bf16x8 ah[4], al[4];
#pragma unroll
        for (int mf = 0; mf < 4; mf++) {
            ah[mf] = *(const bf16x8*)&Ahs[wr + mf * 16 + c16][g * 8];
            al[mf] = *(const bf16x8*)&Als[wr + mf * 16 + c16][g * 8];
        }
#pragma unroll
        for (int nf = 0; nf < 4; nf++) {
            const bf16x8 wh = *(const bf16x8*)&Bhs[wc + nf * 16 + c16][g * 8];
            const bf16x8 wl = *(const bf16x8*)&Bls[wc + nf * 16 + c16][g * 8];
#pragma unroll
            for (int mf = 0; mf < 4; mf++) {
                acc[mf][nf] = __builtin_amdgcn_mfma_f32_16x16x32_bf16(ah[mf], wh, acc[mf][nf], 0, 0, 0);
                acc[mf][nf] = __builtin_amdgcn_mfma_f32_16x16x32_bf16(al[mf], wh, acc[mf][nf], 0, 0, 0);
                acc[mf][nf] = __builtin_amdgcn_mfma_f32_16x16x32_bf16(ah[mf], wl, acc[mf][nf], 0, 0, 0);
            }
        }
    }

#pragma unroll
    for (int mf = 0; mf < 4; mf++) {
#pragma unroll
        for (int nf = 0; nf < 4; nf++) {
            const int n = n0 + wc + nf * 16 + c16;
            const float bval = bo[n];
#pragma unroll
            for (int r = 0; r < 4; r++) {
                const int m = m0 + wr + mf * 16 + g * 4 + r;  // m = b*T + t
                const int t = m & 2047, bb = m >> 11;
                out[((size_t)t * B + bb) * C + n] = acc[mf][nf][r] + bval;
            }
        }
    }
}

// ---------------------------------------------------------------------------
// Flash attention v9 = R11 inner loop (best measured, 144.5 us) with ONE
// change: SINGLE K/V LDS buffer (frags are copied to registers right after
// the barrier anyway, so the double-buffer was redundant). LDS 46 -> 27.6 KB
// lifts the block cap 3 -> 4 blocks/CU for better TRANS/MFMA cross-wave
// overlap. Structure per tile:
//   write LDS(t from regs); ISSUE(t+1);        // global loads span barriers
//   bar1 (lgkm-only); read kf/vf frags -> regs;
//   bar2 (lgkm-only); compute(t)               // next iter's writes follow
// Cross-wave safety: reads(t) precede bar2; writes(t+1) follow bar2.
// ---------------------------------------------------------------------------
__global__ __launch_bounds__(256) void attn_mfma(const unsigned short* __restrict__ Q,
                                                 const unsigned short* __restrict__ K,
                                                 const unsigned short* __restrict__ V,
                                                 const int* __restrict__ mask,
                                                 unsigned short* __restrict__ Xh,
                                                 unsigned short* __restrict__ Xl) {
    __shared__ __align__(16) short Ks[64][72];      // 9216 B
    __shared__ __align__(16) short Vt[64][72];      // 9216 B (transposed V)
    __shared__ __align__(16) short Pl[4][16][72];   // 9216 B wave-private strips

    const int b = blockIdx.z, h = blockIdx.y;
    const int q0 = blockIdx.x * 128;
    const int tid = threadIdx.x;
    const int wl = tid >> 6;
    const int lane = tid & 63;
    const int g = lane >> 4;
    const int c16 = lane & 15;

    const size_t bh = (size_t)(b * H + h) * T * DK;
    const unsigned short* Qg = Q + bh;
    const unsigned short* Kg = K + bh;
    const unsigned short* Vg = V + bh;
    const int* mb = mask + b * T;

    bf16x8 qf[2][2];
#pragma unroll
    for (int qs = 0; qs < 2; qs++)
#pragma unroll
        for (int sl = 0; sl < 2; sl++)
            qf[qs][sl] = *(const bf16x8*)(Qg +
                (size_t)(q0 + wl * 32 + qs * 16 + c16) * DK + g * 8 + sl * 32);

    f32x4 o[2][4] = {};
    float lrow[2] = {0.0f, 0.0f};

    const int skr = tid >> 3;
    const int skc = (tid & 7) * 8;
    const int kp = tid & 31, dc = tid >> 5;
    uint4 kra, krb; u16x8 va, vb; int mw;

#define ISSUE(kv0)                                                              \
    do {                                                                        \
        kra = *(const uint4*)(Kg + (size_t)((kv0) + skr) * DK + skc);           \
        krb = *(const uint4*)(Kg + (size_t)((kv0) + skr + 32) * DK + skc);      \
        va  = *(const u16x8*)(Vg + (size_t)((kv0) + 2 * kp) * DK + dc * 8);     \
        vb  = *(const u16x8*)(Vg + (size_t)((kv0) + 2 * kp + 1) * DK + dc * 8); \
        mw  = mb[(kv0) + lane];                                                 \
    } while (0)

    ISSUE(0);

    for (int kt = 0; kt < NT; ++kt) {
        // ---- write phase: regs -> LDS (compiler inserts vmcnt waits) ----
        const unsigned long long mbits = __ballot(mw != 0);  // before mw clobbered
        *(uint4*)&Ks[skr][skc] = kra;
        *(uint4*)&Ks[skr + 32][skc] = krb;
#pragma unroll
        for (int j = 0; j < 8; j++) {
            *(uint32_t*)&Vt[dc * 8 + j][2 * kp] =
                (uint32_t)(unsigned short)va[j] | ((uint32_t)(unsigned short)vb[j] << 16);
        }
        // ---- prefetch next tile into regs (pending across both barriers) ----
        if (kt + 1 < NT) ISSUE((kt + 1) * 64);

        block_sync_lds();  // RAW: writes(t) visible to all waves

        // K / V fragments -> registers (shared by both q sub-tiles)
        bf16x8 kf[4][2], vf[4][2];
#pragma unroll
        for (int t = 0; t < 4; t++)
#pragma unroll
            for (int sl = 0; sl < 2; sl++) {
                kf[t][sl] = *(const bf16x8*)&Ks[t * 16 + c16][g * 8 + sl * 32];
                vf[t][sl] = *(const bf16x8*)&Vt[t * 16 + c16][g * 8 + sl * 32];
            }

        block_sync_lds();  // WAR: all waves' reads(t) done before writes(t+1)

#pragma unroll
        for (int qs = 0; qs < 2; qs++) {
            // ---- S^T tile: lane holds row q=c16, keys 16t+4g+r ----
            f32x4 s4[4];
#pragma unroll
            for (int t = 0; t < 4; t++) {
                f32x4 acc = {0.f, 0.f, 0.f, 0.f};
                acc = __builtin_amdgcn_mfma_f32_16x16x32_bf16(kf[t][0], qf[qs][0], acc, 0, 0, 0);
                acc = __builtin_amdgcn_mfma_f32_16x16x32_bf16(kf[t][1], qf[qs][1], acc, 0, 0, 0);
                s4[t] = acc;
            }

            // ---- p = exp2(s'), zero masked (bit test), row sum ----
            float rs = 0.0f;
#pragma unroll
            for (int t = 0; t < 4; t++)
#pragma unroll
                for (int r = 0; r < 4; r++) {
                    float p = __builtin_amdgcn_exp2f(s4[t][r]);
                    const int key = 16 * t + 4 * g + r;
                    p = ((mbits >> key) & 1ull) ? 0.0f : p;
                    s4[t][r] = p;
                    rs += p;
                }
            rs += __shfl_xor(rs, 16);
            rs += __shfl_xor(rs, 32);
            lrow[qs] += rs;

            // ---- P row -> wave-private LDS (cvt_pk b32) -> B-fragments ----
            cfence();
#pragma unroll
            for (int t = 0; t < 4; t++)
#pragma unroll
                for (int rr = 0; rr < 2; rr++) {
                    const uint32_t wv = cvtpk_bf16(s4[t][2 * rr], s4[t][2 * rr + 1]);
                    *(uint32_t*)&Pl[wl][c16][16 * t + 4 * g + 2 * rr] = wv;
                }
            cfence();
            bf16x8 pa[2];
            pa[0] = *(const bf16x8*)&Pl[wl][c16][g * 8];
            pa[1] = *(const bf16x8*)&Pl[wl][c16][g * 8 + 32];
            cfence();

            // ---- O^T += V^T P^T ----
#pragma unroll
            for (int td = 0; td < 4; td++) {
                o[qs][td] = __builtin_amdgcn_mfma_f32_16x16x32_bf16(vf[td][0], pa[0], o[qs][td], 0, 0, 0);
                o[qs][td] = __builtin_amdgcn_mfma_f32_16x16x32_bf16(vf[td][1], pa[1], o[qs][td], 0, 0, 0);
            }
        }
    }
#undef ISSUE

#pragma unroll
    for (int qs = 0; qs < 2; qs++) {
        const float inv = 1.0f / lrow[qs];
        const int qq = q0 + wl * 32 + qs * 16 + c16;
#pragma unroll
        for (int td = 0; td < 4; td++) {
            u16x4 hi4, lo4;
#pragma unroll
            for (int r = 0; r < 4; r++) {
                const float val = o[qs][td][r] * inv;
                const unsigned short hv = f2bf(val);
                hi4[r] = hv;
                lo4[r] = f2bf(val - bf2f(hv));
            }
            const size_t idx = ((size_t)b * T + qq) * C + h * DK + td * 16 + 4 * g;
            *(u16x4*)(Xh + idx) = hi4;
            *(u16x4*)(Xl + idx) = lo4;
        }
    }
}

// ---------------------------------------------------------------------------
extern "C" void kernel_launch(void* const* d_in, const int* in_sizes, int n_in,
                              void* d_out, int out_size, void* d_ws, size_t ws_size,
                              hipStream_t stream) {
    const float* query = (const float*)d_in[0];
    const float* key   = (const float*)d_in[1];
    const float* value = (const float*)d_in[2];
    const int*   kpm   = (const int*)d_in[3];
    const float* Wq = (const float*)d_in[4];
    const float* bq = (const float*)d_in[5];
    const float* Wk = (const float*)d_in[6];
    const float* bk = (const float*)d_in[7];
    const float* Wv = (const float*)d_in[8];
    const float* bv = (const float*)d_in[9];
    const float* Wo = (const float*)d_in[10];
    const float* bo = (const float*)d_in[11];

    constexpr size_t MB = 1u << 20;
    char* w8 = (char*)d_ws;
    unsigned short* Qa  = (unsigned short*)(w8 + 0 * MB);   // reused as Xh
    unsigned short* Ka  = (unsigned short*)(w8 + 16 * MB);  // reused as Xl
    unsigned short* Va  = (unsigned short*)(w8 + 32 * MB);
    unsigned short* WB  = (unsigned short*)(w8 + 48 * MB);
    unsigned short* WoH = (unsigned short*)(w8 + 54 * MB);
    unsigned short* WoL = (unsigned short*)(w8 + 56 * MB);
    unsigned short* Qb  = (unsigned short*)(w8 + 64 * MB);
    unsigned short* Kb  = (unsigned short*)(w8 + 80 * MB);
    unsigned short* Vb  = (unsigned short*)(w8 + 96 * MB);
    unsigned short* XhB = Qa;
    unsigned short* XlB = Ka;

    const dim3 blk(256);

    convert_in<<<dim3(4096, 3), blk, 0, stream>>>(query, key, value, Qa, Ka, Va);
    convert_w<<<dim3(512, 3), blk, 0, stream>>>(Wq, Wk, Wv, WB);
    convert_wo<<<dim3(512, 1), blk, 0, stream>>>(Wo, WoH, WoL);

    qkv_gemm<<<dim3(M / 128, 3 * C / 128), blk, 0, stream>>>(Qa, Ka, Va, WB,
                                                             bq, bk, bv,
                                                             Qb, Kb, Vb);

    attn_mfma<<<dim3(T / 128, H, B), blk, 0, stream>>>(Qb, Kb, Vb, kpm, XhB, XlB);

    oproj_gemm<<<dim3(M / 128, C / 128), blk, 0, stream>>>(XhB, XlB, WoH, WoL,
                                                           bo, (float*)d_out);
}

// Round 17
// 270.676 us; speedup vs baseline: 1.1922x; 1.0212x over previous
//
#include <hip/hip_runtime.h>
#include <hip/hip_bf16.h>
#include <cstddef>
#include <cstdint>

constexpr int T  = 2048;
constexpr int B  = 4;
constexpr int C  = 1024;
constexpr int H  = 16;
constexpr int DK = 64;
constexpr int M  = T * B;   // 8192
constexpr int NT = T / 64;  // 32 KV tiles

typedef __attribute__((ext_vector_type(8))) short bf16x8;
typedef __attribute__((ext_vector_type(4))) float f32x4;
typedef __attribute__((ext_vector_type(4))) unsigned short u16x4;
typedef __attribute__((ext_vector_type(8))) unsigned short u16x8;

__device__ inline unsigned short f2bf(float f) {
    union { float f; uint32_t u; } v; v.f = f;
    uint32_t u = v.u + 0x7fff + ((v.u >> 16) & 1);  // RNE
    return (unsigned short)(u >> 16);
}
__device__ inline float bf2f(unsigned short h) {
    union { uint32_t u; float f; } v; v.u = (uint32_t)h << 16;
    return v.f;
}
// HW packed f32->bf16 pair (no builtin on gfx950; T12 recipe)
__device__ inline uint32_t cvtpk_bf16(float lo, float hi) {
    uint32_t r;
    asm("v_cvt_pk_bf16_f32 %0, %1, %2" : "=v"(r) : "v"(lo), "v"(hi));
    return r;
}
// compiler-level full memory fence (no instruction emitted)
__device__ inline void cfence() { asm volatile("" ::: "memory"); }

// Raw workgroup barrier WITHOUT the vmcnt(0) drain __syncthreads emits.
__device__ inline void block_sync_lds() {
    __builtin_amdgcn_sched_barrier(0);
    asm volatile("s_waitcnt lgkmcnt(0)" ::: "memory");
    __builtin_amdgcn_sched_barrier(0);
    __builtin_amdgcn_s_barrier();
    __builtin_amdgcn_sched_barrier(0);
}

// global -> LDS direct DMA, 16B per lane.
__device__ inline void gload_lds16(const void* g, void* l) {
    auto gp = reinterpret_cast<const __attribute__((address_space(1))) char*>(
        reinterpret_cast<uintptr_t>(g));
    auto lp = reinterpret_cast<__attribute__((address_space(3))) char*>(
        reinterpret_cast<uintptr_t>(l));
    __builtin_amdgcn_global_load_lds(gp, lp, 16, 0, 0);
}

// ---------------------------------------------------------------------------
// Input converter (memory-bound, HBM floor) — unchanged from R11.
// ---------------------------------------------------------------------------
__global__ __launch_bounds__(256) void convert_in(const float* __restrict__ q,
                                                  const float* __restrict__ k,
                                                  const float* __restrict__ v,
                                                  unsigned short* __restrict__ dq,
                                                  unsigned short* __restrict__ dk2,
                                                  unsigned short* __restrict__ dv) {
    const float* s; unsigned short* d;
    if (blockIdx.y == 0) { s = q; d = dq; }
    else if (blockIdx.y == 1) { s = k; d = dk2; }
    else { s = v; d = dv; }
    const size_t i = ((size_t)blockIdx.x * 256 + threadIdx.x) * 8;
    const float4 a = *(const float4*)(s + i);
    const float4 b = *(const float4*)(s + i + 4);
    u16x8 o;
    o[0] = f2bf(a.x); o[1] = f2bf(a.y); o[2] = f2bf(a.z); o[3] = f2bf(a.w);
    o[4] = f2bf(b.x); o[5] = f2bf(b.y); o[6] = f2bf(b.z); o[7] = f2bf(b.w);
    *(u16x8*)(d + i) = o;
}

// ---------------------------------------------------------------------------
// Fused weight converter: y=0..2 -> Wq/Wk/Wv into WB[3072][1024] bf16;
// y=3 -> Wo hi/lo split (bf16x3 O-projection). One launch instead of two.
// ---------------------------------------------------------------------------
__global__ __launch_bounds__(256) void convert_weights(
        const float* __restrict__ wq, const float* __restrict__ wk,
        const float* __restrict__ wv, const float* __restrict__ wo,
        unsigned short* __restrict__ wb,
        unsigned short* __restrict__ hi, unsigned short* __restrict__ lo) {
    const int y = blockIdx.y;
    const size_t i = ((size_t)blockIdx.x * 256 + threadIdx.x) * 8;
    if (y < 3) {
        const float* s = y == 0 ? wq : (y == 1 ? wk : wv);
        unsigned short* d = wb + (size_t)y * C * C;
        const float4 a = *(const float4*)(s + i);
        const float4 b = *(const float4*)(s + i + 4);
        u16x8 o;
        o[0] = f2bf(a.x); o[1] = f2bf(a.y); o[2] = f2bf(a.z); o[3] = f2bf(a.w);
        o[4] = f2bf(b.x); o[5] = f2bf(b.y); o[6] = f2bf(b.z); o[7] = f2bf(b.w);
        *(u16x8*)(d + i) = o;
    } else {
#pragma unroll
        for (int j = 0; j < 8; j++) {
            const float x = wo[i + j];
            const unsigned short h = f2bf(x);
            hi[i + j] = h;
            lo[i + j] = f2bf(x - bf2f(h));
        }
    }
}

// ---------------------------------------------------------------------------
// Fused QKV projection GEMM — R11-exact (at m97-structure ceiling ~900 TF):
// bf16 A, gload_lds staging, two __syncthreads per K-step.
// Q scale folds 1/sqrt(DK) * log2(e) for the exp2-based softmax.
// ---------------------------------------------------------------------------
__global__ __launch_bounds__(256) void qkv_gemm(
        const unsigned short* __restrict__ Aq,
        const unsigned short* __restrict__ Ak,
        const unsigned short* __restrict__ Av,
        const unsigned short* __restrict__ W,
        const float* __restrict__ bq, const float* __restrict__ bk,
        const float* __restrict__ bv,
        unsigned short* __restrict__ Qb, unsigned short* __restrict__ Kb,
        unsigned short* __restrict__ Vb) {
    __shared__ __align__(16) unsigned short As[128][32];
    __shared__ __align__(16) unsigned short Ws[128][32];

    const int tid = threadIdx.x;
    const int m0 = blockIdx.x * 128;
    const int n0 = blockIdx.y * 128;
    const int w = tid >> 6, lane = tid & 63;
    const int g = lane >> 4, c16 = lane & 15;
    const int wr = (w >> 1) * 64, wc = (w & 1) * 64;

    const int which = n0 >> 10;  // 0=Q 1=K 2=V (no straddle)
    const unsigned short* A = which == 0 ? Aq : (which == 1 ? Ak : Av);

    f32x4 acc[4][4] = {};

    for (int k0 = 0; k0 < C; k0 += 32) {
        __syncthreads();
#pragma unroll
        for (int half = 0; half < 2; half++) {
            const int chunk = tid + half * 256;       // 0..511
            const int r = chunk >> 2, s = chunk & 3;  // row, 16B slot
            gload_lds16(A + (size_t)(m0 + r) * C + k0 + s * 8,
                        (char*)&As[0][0] + chunk * 16);
            gload_lds16(W + (size_t)(n0 + r) * C + k0 + s * 8,
                        (char*)&Ws[0][0] + chunk * 16);
        }
        __syncthreads();

        bf16x8 af[4], bfr[4];
#pragma unroll
        for (int mf = 0; mf < 4; mf++)
            af[mf] = *(const bf16x8*)&As[wr + mf * 16 + c16][g * 8];
#pragma unroll
        for (int nf = 0; nf < 4; nf++)
            bfr[nf] = *(const bf16x8*)&Ws[wc + nf * 16 + c16][g * 8];
#pragma unroll
        for (int mf = 0; mf < 4; mf++)
#pragma unroll
            for (int nf = 0; nf < 4; nf++)
                acc[mf][nf] = __builtin_amdgcn_mfma_f32_16x16x32_bf16(
                    af[mf], bfr[nf], acc[mf][nf], 0, 0, 0);
    }

    unsigned short* dst = which == 0 ? Qb : (which == 1 ? Kb : Vb);
    const float* bias = which == 0 ? bq : (which == 1 ? bk : bv);
    const float scale = which == 0 ? 0.180336889f : 1.0f;  // 0.125*log2(e) | 1

#pragma unroll
    for (int mf = 0; mf < 4; mf++) {
#pragma unroll
        for (int nf = 0; nf < 4; nf++) {
            const int n = n0 + wc + nf * 16 + c16;
            const int c = n & 1023;
            const int hh = c >> 6, dk = c & 63;
            const float bval = bias[c];
#pragma unroll
            for (int r = 0; r < 4; r++) {
                const int m = m0 + wr + mf * 16 + g * 4 + r;
                const int t = m >> 2, bb = m & 3;             // m = t*B + b
                dst[((size_t)(bb * H + hh) * T + t) * DK + dk] =
                    f2bf((acc[mf][nf][r] + bval) * scale);
            }
        }
    }
}

// ---------------------------------------------------------------------------
// Output projection, bf16x3 (R7/R11 passing structure, ~1140 TF effective).
// ---------------------------------------------------------------------------
__global__ __launch_bounds__(256) void oproj_gemm(
        const unsigned short* __restrict__ Xh, const unsigned short* __restrict__ Xl,
        const unsigned short* __restrict__ Wh, const unsigned short* __restrict__ Wl,
        const float* __restrict__ bo, float* __restrict__ out) {
    __shared__ __align__(16) unsigned short Ahs[128][32];
    __shared__ __align__(16) unsigned short Als[128][32];
    __shared__ __align__(16) unsigned short Bhs[128][32];
    __shared__ __align__(16) unsigned short Bls[128][32];

    const int tid = threadIdx.x;
    const int m0 = blockIdx.x * 128;
    const int n0 = blockIdx.y * 128;
    const int w = tid >> 6, lane = tid & 63;
    const int g = lane >> 4, c16 = lane & 15;
    const int wr = (w >> 1) * 64, wc = (w & 1) * 64;

    f32x4 acc[4][4] = {};

    for (int k0 = 0; k0 < C; k0 += 32) {
        __syncthreads();
#pragma unroll
        for (int half = 0; half < 2; half++) {
            const int chunk = tid + half * 256;
            const int r = chunk >> 2, s = chunk & 3;
            const size_t goffA = (size_t)(m0 + r) * C + k0 + s * 8;
            const size_t goffB = (size_t)(n0 + r) * C + k0 + s * 8;
            gload_lds16(Xh + goffA, (char*)&Ahs[0][0] + chunk * 16);
            gload_lds16(Xl + goffA, (char*)&Als[0][0] + chunk * 16);
            gload_lds16(Wh + goffB, (char*)&Bhs[0][0] + chunk * 16);
            gload_lds16(Wl + goffB, (char*)&Bls[0][0] + chunk * 16);
        }
        __syncthreads();

        bf16x8 ah[4], al[4];
#pragma unroll
        for (int mf = 0; mf < 4; mf++) {
            ah[mf] = *(const bf16x8*)&Ahs[wr + mf * 16 + c16][g * 8];
            al[mf] = *(const bf16x8*)&Als[wr + mf * 16 + c16][g * 8];
        }
#pragma unroll
        for (int nf = 0; nf < 4; nf++) {
            const bf16x8 wh = *(const bf16x8*)&Bhs[wc + nf * 16 + c16][g * 8];
            const bf16x8 wl = *(const bf16x8*)&Bls[wc + nf * 16 + c16][g * 8];
#pragma unroll
            for (int mf = 0; mf < 4; mf++) {
                acc[mf][nf] = __builtin_amdgcn_mfma_f32_16x16x32_bf16(ah[mf], wh, acc[mf][nf], 0, 0, 0);
                acc[mf][nf] = __builtin_amdgcn_mfma_f32_16x16x32_bf16(al[mf], wh, acc[mf][nf], 0, 0, 0);
                acc[mf][nf] = __builtin_amdgcn_mfma_f32_16x16x32_bf16(ah[mf], wl, acc[mf][nf], 0, 0, 0);
            }
        }
    }

#pragma unroll
    for (int mf = 0; mf < 4; mf++) {
#pragma unroll
        for (int nf = 0; nf < 4; nf++) {
            const int n = n0 + wc + nf * 16 + c16;
            const float bval = bo[n];
#pragma unroll
            for (int r = 0; r < 4; r++) {
                const int m = m0 + wr + mf * 16 + g * 4 + r;  // m = b*T + t
                const int t = m & 2047, bb = m >> 11;
                out[((size_t)t * B + bb) * C + n] = acc[mf][nf][r] + bval;
            }
        }
    }
}

// ---------------------------------------------------------------------------
// Flash attention v7 — R11-exact (champion, 144.5 us): double-buffered K/V,
// reg-staged prefetch spanning ONE raw lgkm-only barrier per tile; swapped
// QK^T (lane-local softmax rows), exp2 with log2e folded in Q, bit-test mask
// zeroing, cvt_pk P-pack through wave-private LDS strips.
// ---------------------------------------------------------------------------
__global__ __launch_bounds__(256) void attn_mfma(const unsigned short* __restrict__ Q,
                                                 const unsigned short* __restrict__ K,
                                                 const unsigned short* __restrict__ V,
                                                 const int* __restrict__ mask,
                                                 unsigned short* __restrict__ Xh,
                                                 unsigned short* __restrict__ Xl) {
    __shared__ __align__(16) short Ks[2][64][72];   // 2 x 9216 B
    __shared__ __align__(16) short Vt[2][64][72];   // 2 x 9216 B (transposed V)
    __shared__ __align__(16) short Pl[4][16][72];   //     9216 B wave-private strips

    const int b = blockIdx.z, h = blockIdx.y;
    const int q0 = blockIdx.x * 128;
    const int tid = threadIdx.x;
    const int wl = tid >> 6;
    const int lane = tid & 63;
    const int g = lane >> 4;
    const int c16 = lane & 15;

    const size_t bh = (size_t)(b * H + h) * T * DK;
    const unsigned short* Qg = Q + bh;
    const unsigned short* Kg = K + bh;
    const unsigned short* Vg = V + bh;
    const int* mb = mask + b * T;

    bf16x8 qf[2][2];
#pragma unroll
    for (int qs = 0; qs < 2; qs++)
#pragma unroll
        for (int sl = 0; sl < 2; sl++)
            qf[qs][sl] = *(const bf16x8*)(Qg +
                (size_t)(q0 + wl * 32 + qs * 16 + c16) * DK + g * 8 + sl * 32);

    f32x4 o[2][4] = {};
    float lrow[2] = {0.0f, 0.0f};

    const int skr = tid >> 3;
    const int skc = (tid & 7) * 8;
    const int kp = tid & 31, dc = tid >> 5;
    uint4 kra, krb; u16x8 va, vb; int mw;

#define ISSUE(kv0)                                                              \
    do {                                                                        \
        kra = *(const uint4*)(Kg + (size_t)((kv0) + skr) * DK + skc);           \
        krb = *(const uint4*)(Kg + (size_t)((kv0) + skr + 32) * DK + skc);      \
        va  = *(const u16x8*)(Vg + (size_t)((kv0) + 2 * kp) * DK + dc * 8);     \
        vb  = *(const u16x8*)(Vg + (size_t)((kv0) + 2 * kp + 1) * DK + dc * 8); \
        mw  = mb[(kv0) + lane];                                                 \
    } while (0)

    ISSUE(0);

    for (int kt = 0; kt < NT; ++kt) {
        const int buf = kt & 1;

        const unsigned long long mbits = __ballot(mw != 0);
        *(uint4*)&Ks[buf][skr][skc] = kra;
        *(uint4*)&Ks[buf][skr + 32][skc] = krb;
#pragma unroll
        for (int j = 0; j < 8; j++) {
            *(uint32_t*)&Vt[buf][dc * 8 + j][2 * kp] =
                (uint32_t)(unsigned short)va[j] | ((uint32_t)(unsigned short)vb[j] << 16);
        }
        if (kt + 1 < NT) ISSUE((kt + 1) * 64);

        block_sync_lds();

        bf16x8 kf[4][2], vf[4][2];
#pragma unroll
        for (int t = 0; t < 4; t++)
#pragma unroll
            for (int sl = 0; sl < 2; sl++) {
                kf[t][sl] = *(const bf16x8*)&Ks[buf][t * 16 + c16][g * 8 + sl * 32];
                vf[t][sl] = *(const bf16x8*)&Vt[buf][t * 16 + c16][g * 8 + sl * 32];
            }

#pragma unroll
        for (int qs = 0; qs < 2; qs++) {
            f32x4 s4[4];
#pragma unroll
            for (int t = 0; t < 4; t++) {
                f32x4 acc = {0.f, 0.f, 0.f, 0.f};
                acc = __builtin_amdgcn_mfma_f32_16x16x32_bf16(kf[t][0], qf[qs][0], acc, 0, 0, 0);
                acc = __builtin_amdgcn_mfma_f32_16x16x32_bf16(kf[t][1], qf[qs][1], acc, 0, 0, 0);
                s4[t] = acc;
            }

            float rs = 0.0f;
#pragma unroll
            for (int t = 0; t < 4; t++)
#pragma unroll
                for (int r = 0; r < 4; r++) {
                    float p = __builtin_amdgcn_exp2f(s4[t][r]);
                    const int key = 16 * t + 4 * g + r;
                    p = ((mbits >> key) & 1ull) ? 0.0f : p;
                    s4[t][r] = p;
                    rs += p;
                }
            rs += __shfl_xor(rs, 16);
            rs += __shfl_xor(rs, 32);
            lrow[qs] += rs;

            cfence();
#pragma unroll
            for (int t = 0; t < 4; t++)
#pragma unroll
                for (int rr = 0; rr < 2; rr++) {
                    const uint32_t wv = cvtpk_bf16(s4[t][2 * rr], s4[t][2 * rr + 1]);
                    *(uint32_t*)&Pl[wl][c16][16 * t + 4 * g + 2 * rr] = wv;
                }
            cfence();
            bf16x8 pa[2];
            pa[0] = *(const bf16x8*)&Pl[wl][c16][g * 8];
            pa[1] = *(const bf16x8*)&Pl[wl][c16][g * 8 + 32];
            cfence();

#pragma unroll
            for (int td = 0; td < 4; td++) {
                o[qs][td] = __builtin_amdgcn_mfma_f32_16x16x32_bf16(vf[td][0], pa[0], o[qs][td], 0, 0, 0);
                o[qs][td] = __builtin_amdgcn_mfma_f32_16x16x32_bf16(vf[td][1], pa[1], o[qs][td], 0, 0, 0);
            }
        }
    }
#undef ISSUE

#pragma unroll
    for (int qs = 0; qs < 2; qs++) {
        const float inv = 1.0f / lrow[qs];
        const int qq = q0 + wl * 32 + qs * 16 + c16;
#pragma unroll
        for (int td = 0; td < 4; td++) {
            u16x4 hi4, lo4;
#pragma unroll
            for (int r = 0; r < 4; r++) {
                const float val = o[qs][td][r] * inv;
                const unsigned short hv = f2bf(val);
                hi4[r] = hv;
                lo4[r] = f2bf(val - bf2f(hv));
            }
            const size_t idx = ((size_t)b * T + qq) * C + h * DK + td * 16 + 4 * g;
            *(u16x4*)(Xh + idx) = hi4;
            *(u16x4*)(Xl + idx) = lo4;
        }
    }
}

// ---------------------------------------------------------------------------
extern "C" void kernel_launch(void* const* d_in, const int* in_sizes, int n_in,
                              void* d_out, int out_size, void* d_ws, size_t ws_size,
                              hipStream_t stream) {
    const float* query = (const float*)d_in[0];
    const float* key   = (const float*)d_in[1];
    const float* value = (const float*)d_in[2];
    const int*   kpm   = (const int*)d_in[3];
    const float* Wq = (const float*)d_in[4];
    const float* bq = (const float*)d_in[5];
    const float* Wk = (const float*)d_in[6];
    const float* bk = (const float*)d_in[7];
    const float* Wv = (const float*)d_in[8];
    const float* bv = (const float*)d_in[9];
    const float* Wo = (const float*)d_in[10];
    const float* bo = (const float*)d_in[11];

    constexpr size_t MB = 1u << 20;
    char* w8 = (char*)d_ws;
    unsigned short* Qa  = (unsigned short*)(w8 + 0 * MB);   // reused as Xh
    unsigned short* Ka  = (unsigned short*)(w8 + 16 * MB);  // reused as Xl
    unsigned short* Va  = (unsigned short*)(w8 + 32 * MB);
    unsigned short* WB  = (unsigned short*)(w8 + 48 * MB);
    unsigned short* WoH = (unsigned short*)(w8 + 54 * MB);
    unsigned short* WoL = (unsigned short*)(w8 + 56 * MB);
    unsigned short* Qb  = (unsigned short*)(w8 + 64 * MB);
    unsigned short* Kb  = (unsigned short*)(w8 + 80 * MB);
    unsigned short* Vb  = (unsigned short*)(w8 + 96 * MB);
    unsigned short* XhB = Qa;
    unsigned short* XlB = Ka;

    const dim3 blk(256);

    convert_in<<<dim3(4096, 3), blk, 0, stream>>>(query, key, value, Qa, Ka, Va);
    convert_weights<<<dim3(512, 4), blk, 0, stream>>>(Wq, Wk, Wv, Wo,
                                                      WB, WoH, WoL);

    qkv_gemm<<<dim3(M / 128, 3 * C / 128), blk, 0, stream>>>(Qa, Ka, Va, WB,
                                                             bq, bk, bv,
                                                             Qb, Kb, Vb);

    attn_mfma<<<dim3(T / 128, H, B), blk, 0, stream>>>(Qb, Kb, Vb, kpm, XhB, XlB);

    oproj_gemm<<<dim3(M / 128, C / 128), blk, 0, stream>>>(XhB, XlB, WoH, WoL,
                                                           bo, (float*)d_out);
}